// Round 5
// baseline (4233.869 us; speedup 1.0000x reference)
//
#include <hip/hip_runtime.h>
#include <hip/hip_bf16.h>

#define NPTS 20000
#define NE   320000
#define KNNK 16

// ---- ws layout (float offsets) ---- total 1,662,240 floats = 6,648,960 B
#define OFF_X1   0
#define OFF_SQ   (OFF_X1 + NPTS*64)          // 1,280,000
#define OFF_WB   (OFF_SQ + NPTS)             // 1,300,000
// wbuf sub-offsets (relative floats within wbuf)
#define WB_W1A  0
#define WB_B1A  384
#define WB_W1BT 448
#define WB_B1B  4544
#define WB_W2A  4608      // (128,64) plain
#define WB_B2A  12800
#define WB_W2B  12864     // (64,64) plain
#define WB_B2B  16960
#define WB_WE   17024     // (64,256)
#define WB_BE   33408
#define WB_WP   33664
#define WB_BP   37760
#define WB_WR1  37824
#define WB_BR1  41920
#define WB_WR2  41984
#define WB_BR2  42176
#define WB_TOT  42240
#define OFF_NBR  (OFF_WB + WB_TOT)           // 1,342,240 (int32, 320,000)
#define WS_TOT_FLOATS (OFF_NBR + NPTS*KNNK)
#define WS_NEED_BYTES ((size_t)WS_TOT_FLOATS * 4)

__global__ __launch_bounds__(256) void k_out_zero(float* out, int nelem) {
    int i = blockIdx.x * 256 + threadIdx.x;
    if (i < nelem) out[i] = 0.0f;
}

__global__ __launch_bounds__(256) void k_zero(float* p, int nfloat4) {
    int i = blockIdx.x * 256 + threadIdx.x;
    if (i < nfloat4) { float4 z = {0.f,0.f,0.f,0.f}; ((float4*)p)[i] = z; }
}

// Inputs are fp32 (per reference dtypes); pack into contiguous wbuf (+ two transposes).
__global__ __launch_bounds__(256) void k_prep(
    const float* W1a, const float* b1a,
    const float* W1b, const float* b1b,
    const float* W2a, const float* b2a,
    const float* W2b, const float* b2b,
    const float* We,  const float* be,
    const float* Wp,  const float* bp,
    const float* Wr1, const float* br1,
    const float* Wr2, const float* br2,
    float* wb)
{
    int t = blockIdx.x * blockDim.x + threadIdx.x;
    int gs = gridDim.x * blockDim.x;
    for (int i = t; i < 384;  i += gs) wb[WB_W1A+i] = W1a[i];
    for (int i = t; i < 64;   i += gs) wb[WB_B1A+i] = b1a[i];
    for (int i = t; i < 4096; i += gs) { int j=i>>6, k=i&63; wb[WB_W1BT+i] = W1b[k*64+j]; }
    for (int i = t; i < 64;   i += gs) wb[WB_B1B+i] = b1b[i];
    for (int i = t; i < 8192; i += gs) wb[WB_W2A+i] = W2a[i];
    for (int i = t; i < 64;   i += gs) wb[WB_B2A+i] = b2a[i];
    for (int i = t; i < 4096; i += gs) wb[WB_W2B+i] = W2b[i];
    for (int i = t; i < 64;   i += gs) wb[WB_B2B+i] = b2b[i];
    for (int i = t; i < 16384;i += gs) wb[WB_WE+i]  = We[i];
    for (int i = t; i < 256;  i += gs) wb[WB_BE+i]  = be[i];
    for (int i = t; i < 4096; i += gs) wb[WB_WP+i]  = Wp[i];
    for (int i = t; i < 64;   i += gs) wb[WB_BP+i]  = bp[i];
    for (int i = t; i < 4096; i += gs) wb[WB_WR1+i] = Wr1[i];
    for (int i = t; i < 64;   i += gs) wb[WB_BR1+i] = br1[i];
    for (int i = t; i < 192;  i += gs) wb[WB_WR2+i] = Wr2[i];
    for (int i = t; i < 3;    i += gs) wb[WB_BR2+i] = br2[i];
}

// Stage 1: per-edge MLP (6->64->64, relu both) + atomic segment-max into x1.
// Post-relu values >= 0 -> uint atomicMax over zero-init == segment_max with -inf->0.
__global__ __launch_bounds__(256) void k_edge_mlp(
    const float* __restrict__ dep, const int* __restrict__ ei,
    const float* __restrict__ wb, unsigned int* __restrict__ x1u)
{
    int e = blockIdx.x * 256 + threadIdx.x;
    if (e >= NE) return;
    int s = ei[e];
    int d = ei[NE + e];
    s = s < 0 ? 0 : (s >= NPTS ? NPTS-1 : s);
    d = d < 0 ? 0 : (d >= NPTS ? NPTS-1 : d);
    float xi0 = dep[d*3+0];
    float xi1 = dep[d*3+1];
    float xi2 = dep[d*3+2];
    float xj0 = dep[s*3+0];
    float xj1 = dep[s*3+1];
    float xj2 = dep[s*3+2];
    float in6[6] = { xi0, xi1, xi2, xj0-xi0, xj1-xi1, xj2-xi2 };
    const float* W1a  = wb + WB_W1A;
    const float* b1a  = wb + WB_B1A;
    const float* W1bT = wb + WB_W1BT;
    const float* b1b  = wb + WB_B1B;
    float h1[64];
#pragma unroll
    for (int j = 0; j < 64; ++j) {
        float a = b1a[j];
#pragma unroll
        for (int i = 0; i < 6; ++i) a = fmaf(in6[i], W1a[i*64+j], a);
        h1[j] = fmaxf(a, 0.0f);
    }
    unsigned int* dst = x1u + d*64;
    for (int j = 0; j < 64; ++j) {       // dynamic j: weight row address wave-uniform
        float a = b1b[j];
        const float* wr = W1bT + j*64;
#pragma unroll
        for (int i = 0; i < 64; ++i) a = fmaf(h1[i], wr[i], a);
        a = fmaxf(a, 0.0f);
        atomicMax(dst + j, __float_as_uint(a));
    }
}

__global__ __launch_bounds__(256) void k_sq(const float* __restrict__ x1, float* __restrict__ sq) {
    int n = blockIdx.x * 256 + threadIdx.x;
    if (n >= NPTS) return;
    const float4* r = (const float4*)(x1 + n*64);
    float a = 0.f;
#pragma unroll
    for (int i = 0; i < 16; ++i) { float4 v = r[i]; a += v.x*v.x + v.y*v.y + v.z*v.z + v.w*v.w; }
    sq[n] = a;
}

// KNN over the full candidate range: fused 64q x 64c fp32 dot tiles + running
// per-thread top-16, then in-block merge of the 4 per-thread lists -> exact
// top-16 (lexicographic (d2,idx) asc = lax.top_k tie-break). Writes nbr directly.
#define LSTR 68
__global__ __launch_bounds__(256) void k_knn(
    const float* __restrict__ x1, const float* __restrict__ sqv,
    int* __restrict__ nbr)
{
    __shared__ __align__(16) float qT[64*LSTR];
    __shared__ __align__(16) float cT[64*LSTR];
    __shared__ __align__(16) float dT[64*65];
    int t  = threadIdx.x;
    int n0 = blockIdx.x * 64;

#pragma unroll
    for (int r = 0; r < 16; ++r) {           // q-tile transposed [k][q]
        int f = r*256 + t;
        int q = f >> 6, k = f & 63;
        float v = (n0 + q < NPTS) ? x1[(n0+q)*64 + k] : 0.0f;
        qT[k*LSTR + q] = v;
    }
    int tx = t & 15, ty = t >> 4;
    int qsel = t & 63, sub = t >> 6;         // sub wave-uniform
    float sqq = (n0 + qsel < NPTS) ? sqv[n0 + qsel] : 0.0f;
    float bd[16]; int bi[16];
#pragma unroll
    for (int m = 0; m < 16; ++m) { bd[m] = 1e30f; bi[m] = -1; }
    float wv = 1e30f; int wi = 0;

    const int ntile = (NPTS + 63) / 64;
    for (int tile = 0; tile < ntile; ++tile) {
        int c0 = tile * 64;
#pragma unroll
        for (int r = 0; r < 16; ++r) {       // c-tile transposed [k][c]
            int f = r*256 + t;
            int c = f >> 6, k = f & 63;
            float v = (c0 + c < NPTS) ? x1[(c0+c)*64 + k] : 0.0f;
            cT[k*LSTR + c] = v;
        }
        __syncthreads();
        float acc[4][4];
#pragma unroll
        for (int i = 0; i < 4; ++i)
#pragma unroll
            for (int j = 0; j < 4; ++j) acc[i][j] = 0.f;
#pragma unroll 4
        for (int k = 0; k < 64; ++k) {
            float4 qv = *(const float4*)&qT[k*LSTR + ty*4];   // 272B row pitch: 16B-aligned
            float4 cv = *(const float4*)&cT[k*LSTR + tx*4];
            acc[0][0] = fmaf(cv.x, qv.x, acc[0][0]); acc[0][1] = fmaf(cv.x, qv.y, acc[0][1]);
            acc[0][2] = fmaf(cv.x, qv.z, acc[0][2]); acc[0][3] = fmaf(cv.x, qv.w, acc[0][3]);
            acc[1][0] = fmaf(cv.y, qv.x, acc[1][0]); acc[1][1] = fmaf(cv.y, qv.y, acc[1][1]);
            acc[1][2] = fmaf(cv.y, qv.z, acc[1][2]); acc[1][3] = fmaf(cv.y, qv.w, acc[1][3]);
            acc[2][0] = fmaf(cv.z, qv.x, acc[2][0]); acc[2][1] = fmaf(cv.z, qv.y, acc[2][1]);
            acc[2][2] = fmaf(cv.z, qv.z, acc[2][2]); acc[2][3] = fmaf(cv.z, qv.w, acc[2][3]);
            acc[3][0] = fmaf(cv.w, qv.x, acc[3][0]); acc[3][1] = fmaf(cv.w, qv.y, acc[3][1]);
            acc[3][2] = fmaf(cv.w, qv.z, acc[3][2]); acc[3][3] = fmaf(cv.w, qv.w, acc[3][3]);
        }
#pragma unroll
        for (int i = 0; i < 4; ++i)
#pragma unroll
            for (int j = 0; j < 4; ++j)
                dT[(tx*4+i)*65 + ty*4+j] = acc[i][j];
        __syncthreads();
#pragma unroll
        for (int sidx = 0; sidx < 16; ++sidx) {
            int c = sidx*4 + sub;            // wave-uniform per step
            int cg = c0 + c;
            if (cg < NPTS) {
                float dot = dT[c*65 + qsel];
                float d2 = sqq + sqv[cg] - 2.0f*dot;
                if (d2 < wv) {
#pragma unroll
                    for (int m = 0; m < 16; ++m) if (m == wi) { bd[m] = d2; bi[m] = cg; }
                    wv = bd[0]; wi = 0;
#pragma unroll
                    for (int m = 1; m < 16; ++m) if (bd[m] > wv) { wv = bd[m]; wi = m; }
                }
            }
        }
        __syncthreads();
    }

    // merge the 4 per-thread lists per query (reuse qT=dist, cT=idx)
#pragma unroll
    for (int m = 0; m < 16; ++m) {
        qT[qsel*LSTR + sub*16 + m] = bd[m];
        ((int*)cT)[qsel*LSTR + sub*16 + m] = bi[m];
    }
    __syncthreads();
    if (t < 64 && n0 + t < NPTS) {
        const float* dls = qT + t*LSTR;
        const int*   ils = (const int*)cT + t*LSTR;
        float lastd = -1e38f; int lasti = -1;
        for (int r = 0; r < 16; ++r) {
            float best = 1e30f; int bidx = 0;
            for (int m = 0; m < 64; ++m) {
                float dv = dls[m]; int iv = ils[m];
                bool gt = (dv > lastd) || (dv == lastd && iv > lasti);
                bool lt = (dv < best)  || (dv == best  && iv < bidx);
                if (gt && lt) { best = dv; bidx = iv; }
            }
            bidx = bidx < 0 ? 0 : (bidx >= NPTS ? NPTS-1 : bidx);
            nbr[(n0 + t)*16 + r] = bidx;
            lastd = best; lasti = bidx;
        }
    }
}

// Fused stage-2 MLP (128->64->64, relu, max over 16 nbrs) + head (We/Wp/Wr1/Wr2).
// One 64-thread block per point; x2 never materialized in global. fp32 output.
__global__ __launch_bounds__(64) void k_fuse(
    const float* __restrict__ x1, const int* __restrict__ nbr,
    const float* __restrict__ wb, float* __restrict__ out)
{
    __shared__ float sxr[64];
    __shared__ float svec[64];
    __shared__ float sx2[64];
    __shared__ int   snb[16];
    int n = blockIdx.x;
    int t = threadIdx.x;
    sxr[t] = x1[n*64 + t];
    if (t < 16) snb[t] = nbr[n*16 + t];
    __syncthreads();
    const float* W2a = wb + WB_W2A;   // (128,64)
    const float* W2b = wb + WB_W2B;   // (64,64)
    // A[t] = b2a[t] + sum_i xr[i]*W2a[i][t]  (shared across all k)
    float A = wb[WB_B2A + t];
    for (int i = 0; i < 64; ++i) A = fmaf(sxr[i], W2a[i*64 + t], A);
    float x2v = 0.0f;                 // z_k >= 0 (post-relu), so 0-init == max
    for (int k = 0; k < 16; ++k) {
        int nb = snb[k];
        svec[t] = x1[nb*64 + t];
        __syncthreads();
        float h = A;
        for (int i = 0; i < 64; ++i) h = fmaf(svec[i] - sxr[i], W2a[(64+i)*64 + t], h);
        h = fmaxf(h, 0.f);
        __syncthreads();
        svec[t] = h;
        __syncthreads();
        float z = wb[WB_B2B + t];
        for (int i = 0; i < 64; ++i) z = fmaf(svec[i], W2b[i*64 + t], z);
        x2v = fmaxf(x2v, fmaxf(z, 0.f));
        __syncthreads();
    }
    sx2[t] = x2v;
    __syncthreads();
    const float* We  = wb + WB_WE;
    const float* Wp  = wb + WB_WP;
    const float* Wr1 = wb + WB_WR1;
    const float* Wr2 = wb + WB_WR2;
    for (int r = 0; r < 4; ++r) {
        float xe = wb[WB_BE + r*64 + t];
        for (int i = 0; i < 64; ++i) xe = fmaf(sx2[i], We[i*256 + r*64 + t], xe);
        svec[t] = xe;
        __syncthreads();
        float ft = wb[WB_BP + t];
        for (int i = 0; i < 64; ++i) ft = fmaf(svec[i], Wp[i*64 + t], ft);
        __syncthreads();
        svec[t] = ft;
        __syncthreads();
        float hh = wb[WB_BR1 + t];
        for (int i = 0; i < 64; ++i) hh = fmaf(svec[i], Wr1[i*64 + t], hh);
        hh = fmaxf(hh, 0.f);
        __syncthreads();
        svec[t] = hh;
        __syncthreads();
        if (t < 3) {
            float o = wb[WB_BR2 + t];
            for (int i = 0; i < 64; ++i) o = fmaf(svec[i], Wr2[i*3 + t], o);
            int m = r * NPTS + n;
            out[m*3 + t] = o;
        }
        __syncthreads();
    }
}

extern "C" void kernel_launch(void* const* d_in, const int* in_sizes, int n_in,
                              void* d_out, int out_size, void* d_ws, size_t ws_size,
                              hipStream_t stream)
{
    const float* dep = (const float*)d_in[0];
    const float* W1a = (const float*)d_in[1];
    const float* b1a = (const float*)d_in[2];
    const float* W1b = (const float*)d_in[3];
    const float* b1b = (const float*)d_in[4];
    const float* W2a = (const float*)d_in[5];
    const float* b2a = (const float*)d_in[6];
    const float* W2b = (const float*)d_in[7];
    const float* b2b = (const float*)d_in[8];
    const float* We  = (const float*)d_in[9];
    const float* be  = (const float*)d_in[10];
    const float* Wp  = (const float*)d_in[11];
    const float* bp  = (const float*)d_in[12];
    const float* Wr1 = (const float*)d_in[13];
    const float* br1 = (const float*)d_in[14];
    const float* Wr2 = (const float*)d_in[15];
    const float* br2 = (const float*)d_in[16];
    const int* ei = (const int*)d_in[17];

    // Diagnostic guard: if ws is too small for our plan, fail LOUDLY (absmax)
    // instead of page-faulting. Same behavior on every call -> graph-safe.
    if (ws_size < WS_NEED_BYTES || d_ws == nullptr) {
        k_out_zero<<<(out_size + 255)/256, 256, 0, stream>>>((float*)d_out, out_size);
        return;
    }

    float* ws   = (float*)d_ws;
    float* x1   = ws + OFF_X1;
    float* sq   = ws + OFF_SQ;
    float* wbuf = ws + OFF_WB;
    int*   nbr  = (int*)(ws + OFF_NBR);

    k_zero<<<(NPTS*64/4 + 255)/256, 256, 0, stream>>>(x1, NPTS*64/4);
    k_prep<<<64, 256, 0, stream>>>(W1a,b1a,W1b,b1b,W2a,b2a,W2b,b2b,We,be,Wp,bp,Wr1,br1,Wr2,br2, wbuf);
    k_edge_mlp<<<NE/256, 256, 0, stream>>>(dep, ei, wbuf, (unsigned int*)x1);
    k_sq<<<(NPTS+255)/256, 256, 0, stream>>>(x1, sq);
    k_knn<<<(NPTS+63)/64, 256, 0, stream>>>(x1, sq, nbr);
    k_fuse<<<NPTS, 64, 0, stream>>>(x1, nbr, wbuf, (float*)d_out);
}

// Round 6
// 3634.346 us; speedup vs baseline: 1.1650x; 1.1650x over previous
//
#include <hip/hip_runtime.h>
#include <hip/hip_bf16.h>

#define NPTS 20000
#define NE   320000
#define KNNK 16

// ---- ws layout (float offsets) ---- total 1,662,240 floats = 6,648,960 B
#define OFF_X1   0
#define OFF_SQ   (OFF_X1 + NPTS*64)          // 1,280,000
#define OFF_WB   (OFF_SQ + NPTS)             // 1,300,000
// wbuf sub-offsets (relative floats within wbuf)
#define WB_W1A  0
#define WB_B1A  384
#define WB_W1BT 448
#define WB_B1B  4544
#define WB_W2A  4608      // (128,64) plain
#define WB_B2A  12800
#define WB_W2B  12864     // (64,64) plain
#define WB_B2B  16960
#define WB_WE   17024     // (64,256)
#define WB_BE   33408
#define WB_WP   33664
#define WB_BP   37760
#define WB_WR1  37824
#define WB_BR1  41920
#define WB_WR2  41984
#define WB_BR2  42176
#define WB_TOT  42240
#define OFF_NBR  (OFF_WB + WB_TOT)           // 1,342,240 (int32, 320,000)
#define WS_TOT_FLOATS (OFF_NBR + NPTS*KNNK)
#define WS_NEED_BYTES ((size_t)WS_TOT_FLOATS * 4)

__global__ __launch_bounds__(256) void k_out_zero(float* out, int nelem) {
    int i = blockIdx.x * 256 + threadIdx.x;
    if (i < nelem) out[i] = 0.0f;
}

__global__ __launch_bounds__(256) void k_zero(float* p, int nfloat4) {
    int i = blockIdx.x * 256 + threadIdx.x;
    if (i < nfloat4) { float4 z = {0.f,0.f,0.f,0.f}; ((float4*)p)[i] = z; }
}

__global__ __launch_bounds__(256) void k_prep(
    const float* W1a, const float* b1a,
    const float* W1b, const float* b1b,
    const float* W2a, const float* b2a,
    const float* W2b, const float* b2b,
    const float* We,  const float* be,
    const float* Wp,  const float* bp,
    const float* Wr1, const float* br1,
    const float* Wr2, const float* br2,
    float* wb)
{
    int t = blockIdx.x * blockDim.x + threadIdx.x;
    int gs = gridDim.x * blockDim.x;
    for (int i = t; i < 384;  i += gs) wb[WB_W1A+i] = W1a[i];
    for (int i = t; i < 64;   i += gs) wb[WB_B1A+i] = b1a[i];
    for (int i = t; i < 4096; i += gs) { int j=i>>6, k=i&63; wb[WB_W1BT+i] = W1b[k*64+j]; }
    for (int i = t; i < 64;   i += gs) wb[WB_B1B+i] = b1b[i];
    for (int i = t; i < 8192; i += gs) wb[WB_W2A+i] = W2a[i];
    for (int i = t; i < 64;   i += gs) wb[WB_B2A+i] = b2a[i];
    for (int i = t; i < 4096; i += gs) wb[WB_W2B+i] = W2b[i];
    for (int i = t; i < 64;   i += gs) wb[WB_B2B+i] = b2b[i];
    for (int i = t; i < 16384;i += gs) wb[WB_WE+i]  = We[i];
    for (int i = t; i < 256;  i += gs) wb[WB_BE+i]  = be[i];
    for (int i = t; i < 4096; i += gs) wb[WB_WP+i]  = Wp[i];
    for (int i = t; i < 64;   i += gs) wb[WB_BP+i]  = bp[i];
    for (int i = t; i < 4096; i += gs) wb[WB_WR1+i] = Wr1[i];
    for (int i = t; i < 64;   i += gs) wb[WB_BR1+i] = br1[i];
    for (int i = t; i < 192;  i += gs) wb[WB_WR2+i] = Wr2[i];
    for (int i = t; i < 3;    i += gs) wb[WB_BR2+i] = br2[i];
}

// Stage 1: per-edge MLP (6->64->64, relu both) + atomic segment-max into x1.
// Post-relu >= 0 -> uint atomicMax over zero-init == segment_max with -inf->0.
// Channel order staggered per (block,wave) to spread atomic contention; jj stays
// wave-uniform so weight-row addressing remains scalar (s_load).
__global__ __launch_bounds__(256) void k_edge_mlp(
    const float* __restrict__ dep, const int* __restrict__ ei,
    const float* __restrict__ wb, unsigned int* __restrict__ x1u)
{
    int e = blockIdx.x * 256 + threadIdx.x;
    if (e >= NE) return;
    int s = ei[e];
    int d = ei[NE + e];
    s = s < 0 ? 0 : (s >= NPTS ? NPTS-1 : s);
    d = d < 0 ? 0 : (d >= NPTS ? NPTS-1 : d);
    float xi0 = dep[d*3+0];
    float xi1 = dep[d*3+1];
    float xi2 = dep[d*3+2];
    float xj0 = dep[s*3+0];
    float xj1 = dep[s*3+1];
    float xj2 = dep[s*3+2];
    float in6[6] = { xi0, xi1, xi2, xj0-xi0, xj1-xi1, xj2-xi2 };
    const float* W1a  = wb + WB_W1A;
    const float* b1a  = wb + WB_B1A;
    const float* W1bT = wb + WB_W1BT;
    const float* b1b  = wb + WB_B1B;
    float h1[64];
#pragma unroll
    for (int j = 0; j < 64; ++j) {
        float a = b1a[j];
#pragma unroll
        for (int i = 0; i < 6; ++i) a = fmaf(in6[i], W1a[i*64+j], a);
        h1[j] = fmaxf(a, 0.0f);
    }
    unsigned int* dst = x1u + d*64;
    int woff = (((blockIdx.x << 2) + (threadIdx.x >> 6)) & 3) << 4;  // wave-uniform
    for (int j = 0; j < 64; ++j) {
        int jj = (j + woff) & 63;
        float a = b1b[jj];
        const float* wr = W1bT + jj*64;
#pragma unroll
        for (int i = 0; i < 64; ++i) a = fmaf(h1[i], wr[i], a);
        a = fmaxf(a, 0.0f);
        atomicMax(dst + jj, __float_as_uint(a));
    }
}

__global__ __launch_bounds__(256) void k_sq(const float* __restrict__ x1, float* __restrict__ sq) {
    int n = blockIdx.x * 256 + threadIdx.x;
    if (n >= NPTS) return;
    const float4* r = (const float4*)(x1 + n*64);
    float a = 0.f;
#pragma unroll
    for (int i = 0; i < 16; ++i) { float4 v = r[i]; a += v.x*v.x + v.y*v.y + v.z*v.z + v.w*v.w; }
    sq[n] = a;
}

// KNN v2: 512 threads (8 waves), 64q x 128c fp32 tiles, conflict-free LDS.
// Wave w: qs=w>>1 (16q strip), cs=w&1 (64c strip); lane: 4q x 4c register tile.
// dT[q][c] (pitch 132 = 4*33) aliases cT between k-loop and next staging.
// Selection: 256 threads (q=t&63, sub=(t>>6)&3, 32 c each), exact in-block merge.
#define QTP 68
#define CTP 132
__global__ __launch_bounds__(512) void k_knn(
    const float* __restrict__ x1, const float* __restrict__ sqv,
    int* __restrict__ nbr)
{
    __shared__ __align__(16) float smem[64*QTP + 64*CTP];   // 12800 floats
    __shared__ __align__(16) float ssq[128];
    float* qT = smem;                 // [64][QTP]  (k-major, q inner)
    float* cT = smem + 64*QTP;        // [64][CTP]  (k-major, c inner)
    float* dT = cT;                   // alias: [64 q][CTP c]
    float* fd = smem;                 // final dump [64][65]
    int*   fi = (int*)(smem + 64*65); // [64][65]
    const int t  = threadIdx.x;
    const int n0 = blockIdx.x * 64;

    // stage qT transposed [k][q]; lane-stride-1 stores -> conflict-free
#pragma unroll
    for (int i = 0; i < 2; ++i) {
        int f = i*512 + t;
        int q = f & 63, kc = f >> 6;
        float4 v = make_float4(0.f,0.f,0.f,0.f);
        if (n0 + q < NPTS) v = *(const float4*)&x1[(n0+q)*64 + kc*4];
        qT[(kc*4+0)*QTP + q] = v.x;
        qT[(kc*4+1)*QTP + q] = v.y;
        qT[(kc*4+2)*QTP + q] = v.z;
        qT[(kc*4+3)*QTP + q] = v.w;
    }
    const int w  = t >> 6;
    const int qs = w >> 1, cs = w & 1;
    const int tx = t & 15, ty = (t >> 4) & 3;
    const int qb = qs*16 + ty*4;
    const int cb = cs*64 + tx*4;
    const int selq = t & 63, sub = (t >> 6) & 3;
    const bool selact = (t < 256);
    float sqq = (n0 + selq < NPTS) ? sqv[n0 + selq] : 0.0f;
    float bd[16]; int bi[16];
#pragma unroll
    for (int m = 0; m < 16; ++m) { bd[m] = 1e30f; bi[m] = -1; }
    float wv = 1e30f; int wi = 0;

    const int ntile = (NPTS + 127) / 128;
    for (int tile = 0; tile < ntile; ++tile) {
        const int c0 = tile * 128;
        __syncthreads();   // prev-iter dT reads done before cT overwrite
#pragma unroll
        for (int i = 0; i < 4; ++i) {
            int f = i*512 + t;
            int c = f & 127, kc = f >> 7;
            float4 v = make_float4(0.f,0.f,0.f,0.f);
            if (c0 + c < NPTS) v = *(const float4*)&x1[(c0+c)*64 + kc*4];
            cT[(kc*4+0)*CTP + c] = v.x;
            cT[(kc*4+1)*CTP + c] = v.y;
            cT[(kc*4+2)*CTP + c] = v.z;
            cT[(kc*4+3)*CTP + c] = v.w;
        }
        if (t < 128) ssq[t] = (c0 + t < NPTS) ? sqv[c0 + t] : 1e30f;
        __syncthreads();
        float acc[4][4];
#pragma unroll
        for (int i = 0; i < 4; ++i)
#pragma unroll
            for (int j = 0; j < 4; ++j) acc[i][j] = 0.f;
#pragma unroll 4
        for (int k = 0; k < 64; ++k) {
            float4 qv = *(const float4*)&qT[k*QTP + qb];
            float4 cv = *(const float4*)&cT[k*CTP + cb];
            acc[0][0] = fmaf(cv.x, qv.x, acc[0][0]); acc[0][1] = fmaf(cv.x, qv.y, acc[0][1]);
            acc[0][2] = fmaf(cv.x, qv.z, acc[0][2]); acc[0][3] = fmaf(cv.x, qv.w, acc[0][3]);
            acc[1][0] = fmaf(cv.y, qv.x, acc[1][0]); acc[1][1] = fmaf(cv.y, qv.y, acc[1][1]);
            acc[1][2] = fmaf(cv.y, qv.z, acc[1][2]); acc[1][3] = fmaf(cv.y, qv.w, acc[1][3]);
            acc[2][0] = fmaf(cv.z, qv.x, acc[2][0]); acc[2][1] = fmaf(cv.z, qv.y, acc[2][1]);
            acc[2][2] = fmaf(cv.z, qv.z, acc[2][2]); acc[2][3] = fmaf(cv.z, qv.w, acc[2][3]);
            acc[3][0] = fmaf(cv.w, qv.x, acc[3][0]); acc[3][1] = fmaf(cv.w, qv.y, acc[3][1]);
            acc[3][2] = fmaf(cv.w, qv.z, acc[3][2]); acc[3][3] = fmaf(cv.w, qv.w, acc[3][3]);
        }
        __syncthreads();   // all cT reads done; dT may overwrite
        // dT[q][c]: lane's 4 c-values contiguous -> b128; balanced across bank-groups
#pragma unroll
        for (int j = 0; j < 4; ++j) {
            float4 o;
            o.x = acc[0][j]; o.y = acc[1][j]; o.z = acc[2][j]; o.w = acc[3][j];
            *(float4*)&dT[(qb + j)*CTP + cb] = o;
        }
        __syncthreads();
        if (selact) {
#pragma unroll
            for (int ii = 0; ii < 8; ++ii) {
                int cc = sub*32 + ii*4;
                float4 dv = *(const float4*)&dT[selq*CTP + cc];
                float dd[4] = {dv.x, dv.y, dv.z, dv.w};
#pragma unroll
                for (int e = 0; e < 4; ++e) {
                    int cg = c0 + cc + e;
                    if (cg < NPTS) {
                        float d2 = sqq + ssq[cc+e] - 2.0f*dd[e];
                        if (d2 < wv) {
#pragma unroll
                            for (int m = 0; m < 16; ++m) if (m == wi) { bd[m] = d2; bi[m] = cg; }
                            wv = bd[0]; wi = 0;
#pragma unroll
                            for (int m = 1; m < 16; ++m) if (bd[m] > wv) { wv = bd[m]; wi = m; }
                        }
                    }
                }
            }
        }
    }
    __syncthreads();   // qT/cT/dT all dead; reuse as dump area
    if (selact) {
#pragma unroll
        for (int m = 0; m < 16; ++m) {
            fd[selq*65 + sub*16 + m] = bd[m];
            fi[selq*65 + sub*16 + m] = bi[m];
        }
    }
    __syncthreads();
    if (t < 64 && n0 + t < NPTS) {
        const float* dls = fd + t*65;
        const int*   ils = fi + t*65;
        float lastd = -1e38f; int lasti = -1;
        for (int r = 0; r < 16; ++r) {
            float best = 1e30f; int bidx = 0;
            for (int m = 0; m < 64; ++m) {
                float dv2 = dls[m]; int iv = ils[m];
                bool gt = (dv2 > lastd) || (dv2 == lastd && iv > lasti);
                bool lt = (dv2 < best)  || (dv2 == best  && iv < bidx);
                if (gt && lt) { best = dv2; bidx = iv; }
            }
            int bc = bidx < 0 ? 0 : (bidx >= NPTS ? NPTS-1 : bidx);
            nbr[(n0 + t)*16 + r] = bc;
            lastd = best; lasti = bidx;
        }
    }
}

// Fused stage-2 MLP (128->64->64, relu, max over 16 nbrs) + head (We/Wp/Wr1/Wr2).
// One 64-thread block per point; x2 never materialized in global. fp32 output.
__global__ __launch_bounds__(64) void k_fuse(
    const float* __restrict__ x1, const int* __restrict__ nbr,
    const float* __restrict__ wb, float* __restrict__ out)
{
    __shared__ float sxr[64];
    __shared__ float svec[64];
    __shared__ float sx2[64];
    __shared__ int   snb[16];
    int n = blockIdx.x;
    int t = threadIdx.x;
    sxr[t] = x1[n*64 + t];
    if (t < 16) snb[t] = nbr[n*16 + t];
    __syncthreads();
    const float* W2a = wb + WB_W2A;   // (128,64)
    const float* W2b = wb + WB_W2B;   // (64,64)
    float A = wb[WB_B2A + t];
    for (int i = 0; i < 64; ++i) A = fmaf(sxr[i], W2a[i*64 + t], A);
    float x2v = 0.0f;                 // z_k >= 0 (post-relu), so 0-init == max
    for (int k = 0; k < 16; ++k) {
        int nb = snb[k];
        svec[t] = x1[nb*64 + t];
        __syncthreads();
        float h = A;
        for (int i = 0; i < 64; ++i) h = fmaf(svec[i] - sxr[i], W2a[(64+i)*64 + t], h);
        h = fmaxf(h, 0.f);
        __syncthreads();
        svec[t] = h;
        __syncthreads();
        float z = wb[WB_B2B + t];
        for (int i = 0; i < 64; ++i) z = fmaf(svec[i], W2b[i*64 + t], z);
        x2v = fmaxf(x2v, fmaxf(z, 0.f));
        __syncthreads();
    }
    sx2[t] = x2v;
    __syncthreads();
    const float* We  = wb + WB_WE;
    const float* Wp  = wb + WB_WP;
    const float* Wr1 = wb + WB_WR1;
    const float* Wr2 = wb + WB_WR2;
    for (int r = 0; r < 4; ++r) {
        float xe = wb[WB_BE + r*64 + t];
        for (int i = 0; i < 64; ++i) xe = fmaf(sx2[i], We[i*256 + r*64 + t], xe);
        svec[t] = xe;
        __syncthreads();
        float ft = wb[WB_BP + t];
        for (int i = 0; i < 64; ++i) ft = fmaf(svec[i], Wp[i*64 + t], ft);
        __syncthreads();
        svec[t] = ft;
        __syncthreads();
        float hh = wb[WB_BR1 + t];
        for (int i = 0; i < 64; ++i) hh = fmaf(svec[i], Wr1[i*64 + t], hh);
        hh = fmaxf(hh, 0.f);
        __syncthreads();
        svec[t] = hh;
        __syncthreads();
        if (t < 3) {
            float o = wb[WB_BR2 + t];
            for (int i = 0; i < 64; ++i) o = fmaf(svec[i], Wr2[i*3 + t], o);
            int m = r * NPTS + n;
            out[m*3 + t] = o;
        }
        __syncthreads();
    }
}

extern "C" void kernel_launch(void* const* d_in, const int* in_sizes, int n_in,
                              void* d_out, int out_size, void* d_ws, size_t ws_size,
                              hipStream_t stream)
{
    const float* dep = (const float*)d_in[0];
    const float* W1a = (const float*)d_in[1];
    const float* b1a = (const float*)d_in[2];
    const float* W1b = (const float*)d_in[3];
    const float* b1b = (const float*)d_in[4];
    const float* W2a = (const float*)d_in[5];
    const float* b2a = (const float*)d_in[6];
    const float* W2b = (const float*)d_in[7];
    const float* b2b = (const float*)d_in[8];
    const float* We  = (const float*)d_in[9];
    const float* be  = (const float*)d_in[10];
    const float* Wp  = (const float*)d_in[11];
    const float* bp  = (const float*)d_in[12];
    const float* Wr1 = (const float*)d_in[13];
    const float* br1 = (const float*)d_in[14];
    const float* Wr2 = (const float*)d_in[15];
    const float* br2 = (const float*)d_in[16];
    const int* ei = (const int*)d_in[17];

    if (ws_size < WS_NEED_BYTES || d_ws == nullptr) {
        k_out_zero<<<(out_size + 255)/256, 256, 0, stream>>>((float*)d_out, out_size);
        return;
    }

    float* ws   = (float*)d_ws;
    float* x1   = ws + OFF_X1;
    float* sq   = ws + OFF_SQ;
    float* wbuf = ws + OFF_WB;
    int*   nbr  = (int*)(ws + OFF_NBR);

    k_zero<<<(NPTS*64/4 + 255)/256, 256, 0, stream>>>(x1, NPTS*64/4);
    k_prep<<<64, 256, 0, stream>>>(W1a,b1a,W1b,b1b,W2a,b2a,W2b,b2b,We,be,Wp,bp,Wr1,br1,Wr2,br2, wbuf);
    k_edge_mlp<<<NE/256, 256, 0, stream>>>(dep, ei, wbuf, (unsigned int*)x1);
    k_sq<<<(NPTS+255)/256, 256, 0, stream>>>(x1, sq);
    k_knn<<<(NPTS+63)/64, 512, 0, stream>>>(x1, sq, nbr);
    k_fuse<<<NPTS, 64, 0, stream>>>(x1, nbr, wbuf, (float*)d_out);
}

// Round 7
// 2739.720 us; speedup vs baseline: 1.5454x; 1.3265x over previous
//
#include <hip/hip_runtime.h>
#include <hip/hip_bf16.h>

#define NPTS 20000
#define NE   320000
#define KNNK 16

typedef __attribute__((ext_vector_type(8))) short bf16x8;
typedef __attribute__((ext_vector_type(4))) float f32x4;

// ---- ws layout (float offsets) ---- total 1,662,240 floats = 6,648,960 B
// x1 region: per-row 256B = [64 bf16 hi | 64 bf16 lo] after k_conv (fp32 before)
#define OFF_X1   0
#define OFF_SQ   (OFF_X1 + NPTS*64)          // 1,280,000
#define OFF_WB   (OFF_SQ + NPTS)             // 1,300,000
#define WB_W1A  0
#define WB_B1A  384
#define WB_W1BT 448
#define WB_B1B  4544
#define WB_W2A  4608      // (128,64)
#define WB_B2A  12800
#define WB_W2B  12864     // (64,64)
#define WB_B2B  16960
#define WB_WE   17024     // (64,256)
#define WB_BE   33408
#define WB_WP   33664
#define WB_BP   37760
#define WB_WR1  37824
#define WB_BR1  41920
#define WB_WR2  41984
#define WB_BR2  42176
#define WB_TOT  42240
#define OFF_NBR  (OFF_WB + WB_TOT)           // int32, 320,000
#define WS_TOT_FLOATS (OFF_NBR + NPTS*KNNK)
#define WS_NEED_BYTES ((size_t)WS_TOT_FLOATS * 4)

__global__ __launch_bounds__(256) void k_out_zero(float* out, int nelem) {
    int i = blockIdx.x * 256 + threadIdx.x;
    if (i < nelem) out[i] = 0.0f;
}

__global__ __launch_bounds__(256) void k_zero(float* p, int nfloat4) {
    int i = blockIdx.x * 256 + threadIdx.x;
    if (i < nfloat4) { float4 z = {0.f,0.f,0.f,0.f}; ((float4*)p)[i] = z; }
}

__global__ __launch_bounds__(256) void k_prep(
    const float* W1a, const float* b1a,
    const float* W1b, const float* b1b,
    const float* W2a, const float* b2a,
    const float* W2b, const float* b2b,
    const float* We,  const float* be,
    const float* Wp,  const float* bp,
    const float* Wr1, const float* br1,
    const float* Wr2, const float* br2,
    float* wb)
{
    int t = blockIdx.x * blockDim.x + threadIdx.x;
    int gs = gridDim.x * blockDim.x;
    for (int i = t; i < 384;  i += gs) wb[WB_W1A+i] = W1a[i];
    for (int i = t; i < 64;   i += gs) wb[WB_B1A+i] = b1a[i];
    for (int i = t; i < 4096; i += gs) { int j=i>>6, k=i&63; wb[WB_W1BT+i] = W1b[k*64+j]; }
    for (int i = t; i < 64;   i += gs) wb[WB_B1B+i] = b1b[i];
    for (int i = t; i < 8192; i += gs) wb[WB_W2A+i] = W2a[i];
    for (int i = t; i < 64;   i += gs) wb[WB_B2A+i] = b2a[i];
    for (int i = t; i < 4096; i += gs) wb[WB_W2B+i] = W2b[i];
    for (int i = t; i < 64;   i += gs) wb[WB_B2B+i] = b2b[i];
    for (int i = t; i < 16384;i += gs) wb[WB_WE+i]  = We[i];
    for (int i = t; i < 256;  i += gs) wb[WB_BE+i]  = be[i];
    for (int i = t; i < 4096; i += gs) wb[WB_WP+i]  = Wp[i];
    for (int i = t; i < 64;   i += gs) wb[WB_BP+i]  = bp[i];
    for (int i = t; i < 4096; i += gs) wb[WB_WR1+i] = Wr1[i];
    for (int i = t; i < 64;   i += gs) wb[WB_BR1+i] = br1[i];
    for (int i = t; i < 192;  i += gs) wb[WB_WR2+i] = Wr2[i];
    for (int i = t; i < 3;    i += gs) wb[WB_BR2+i] = br2[i];
}

// Stage 1: per-edge MLP (6->64->64, relu both) + atomic segment-max into x1 (fp32).
__global__ __launch_bounds__(256) void k_edge_mlp(
    const float* __restrict__ dep, const int* __restrict__ ei,
    const float* __restrict__ wb, unsigned int* __restrict__ x1u)
{
    int e = blockIdx.x * 256 + threadIdx.x;
    if (e >= NE) return;
    int s = ei[e];
    int d = ei[NE + e];
    s = s < 0 ? 0 : (s >= NPTS ? NPTS-1 : s);
    d = d < 0 ? 0 : (d >= NPTS ? NPTS-1 : d);
    float xi0 = dep[d*3+0];
    float xi1 = dep[d*3+1];
    float xi2 = dep[d*3+2];
    float xj0 = dep[s*3+0];
    float xj1 = dep[s*3+1];
    float xj2 = dep[s*3+2];
    float in6[6] = { xi0, xi1, xi2, xj0-xi0, xj1-xi1, xj2-xi2 };
    const float* W1a  = wb + WB_W1A;
    const float* b1a  = wb + WB_B1A;
    const float* W1bT = wb + WB_W1BT;
    const float* b1b  = wb + WB_B1B;
    float h1[64];
#pragma unroll
    for (int j = 0; j < 64; ++j) {
        float a = b1a[j];
#pragma unroll
        for (int i = 0; i < 6; ++i) a = fmaf(in6[i], W1a[i*64+j], a);
        h1[j] = fmaxf(a, 0.0f);
    }
    unsigned int* dst = x1u + d*64;
    int woff = (((blockIdx.x << 2) + (threadIdx.x >> 6)) & 3) << 4;  // wave-uniform
    for (int j = 0; j < 64; ++j) {
        int jj = (j + woff) & 63;
        float a = b1b[jj];
        const float* wr = W1bT + jj*64;
#pragma unroll
        for (int i = 0; i < 64; ++i) a = fmaf(h1[i], wr[i], a);
        a = fmaxf(a, 0.0f);
        atomicMax(dst + jj, __float_as_uint(a));
    }
}

// Convert x1 rows fp32 -> [hi bf16 x64 | lo bf16 x64] IN PLACE, and write sq (from fp32).
__global__ __launch_bounds__(256) void k_conv(float* __restrict__ x1, float* __restrict__ sq) {
    int n = blockIdx.x * 256 + threadIdx.x;
    if (n >= NPTS) return;
    float* base = x1 + n*64;
    float4 r[16];
#pragma unroll
    for (int i = 0; i < 16; ++i) r[i] = ((const float4*)base)[i];
    float s = 0.f;
#pragma unroll
    for (int i = 0; i < 16; ++i) s += r[i].x*r[i].x + r[i].y*r[i].y + r[i].z*r[i].z + r[i].w*r[i].w;
    sq[n] = s;
    unsigned int* hi = (unsigned int*)base;          // bytes [0,128)
    unsigned int* lo = (unsigned int*)(base + 32);   // bytes [128,256)
#pragma unroll
    for (int j = 0; j < 8; ++j) {
        float v[8] = { r[2*j].x, r[2*j].y, r[2*j].z, r[2*j].w,
                       r[2*j+1].x, r[2*j+1].y, r[2*j+1].z, r[2*j+1].w };
        unsigned int hb[8], lb[8];
#pragma unroll
        for (int e = 0; e < 8; ++e) {
            unsigned int u = __float_as_uint(v[e]);
            hb[e] = (u + 0x7fffu + ((u >> 16) & 1u)) >> 16;           // RNE bf16
            float hf = __uint_as_float(hb[e] << 16);
            float lf = v[e] - hf;
            unsigned int ul = __float_as_uint(lf);
            lb[e] = (ul + 0x7fffu + ((ul >> 16) & 1u)) >> 16;
        }
        uint4 hp, lp;
        hp.x = hb[0] | (hb[1] << 16); hp.y = hb[2] | (hb[3] << 16);
        hp.z = hb[4] | (hb[5] << 16); hp.w = hb[6] | (hb[7] << 16);
        lp.x = lb[0] | (lb[1] << 16); lp.y = lb[2] | (lb[3] << 16);
        lp.z = lb[4] | (lb[5] << 16); lp.w = lb[6] | (lb[7] << 16);
        ((uint4*)hi)[j] = hp;
        ((uint4*)lo)[j] = lp;
    }
}

// KNN v3 (MFMA split-bf16): 512 threads, 64q x 128c tiles.
// dot(q,c) via 3x mfma_f32_16x16x32_bf16 per K-half (hh + lh + hl), fp32 acc.
// Layouts (guide-verified): A m=lane&15,k=quad*8+j ; B n=lane&15,k=quad*8+j ;
// C/D col=lane&15,row=quad*4+reg. Score = sqc - 2*dot (sqq constant per query).
#define RP  136   // staging row pitch in shorts (272 B): balanced banks
#define DTP 140   // dT pitch in words: quad-stride 560B = 2-way only
__global__ __launch_bounds__(512, 2) void k_knn(
    const float* __restrict__ x1, const float* __restrict__ sqv,
    int* __restrict__ nbr)
{
    __shared__ __align__(16) unsigned short qbuf[64*RP];       // 17408 B
    __shared__ __align__(16) unsigned char  cbuf_raw[64*DTP*4];// 35840 B (c-tiles, dT alias)
    __shared__ float ssq[128];
    unsigned short* cbuf = (unsigned short*)cbuf_raw;          // [128][RP]
    float* dT = (float*)cbuf_raw;                              // [64][DTP]
    const int t  = threadIdx.x;
    const int n0 = blockIdx.x * 64;

    // stage q tile: 64 rows x 256 B (hi|lo) -> qbuf rows
#pragma unroll
    for (int i = 0; i < 2; ++i) {
        int ch = i*512 + t;
        int row = ch >> 4, off = ch & 15;
        uint4 v = make_uint4(0,0,0,0);
        if (n0 + row < NPTS) v = ((const uint4*)(x1 + (n0+row)*64))[off];
        *(uint4*)&qbuf[row*RP + off*8] = v;
    }
    __syncthreads();

    const int lane15 = t & 15;
    const int quad   = (t >> 4) & 3;
    const int w  = t >> 6;
    const int qs = w >> 1, cs = w & 1;
    bf16x8 Ah[2], Al[2];
    {
        const unsigned short* qr = &qbuf[(qs*16 + lane15)*RP + quad*8];
        Ah[0] = *(const bf16x8*)(qr);
        Ah[1] = *(const bf16x8*)(qr + 32);
        Al[0] = *(const bf16x8*)(qr + 64);
        Al[1] = *(const bf16x8*)(qr + 96);
    }
    const int selq = t & 63, sub = (t >> 6) & 3;
    const bool selact = (t < 256);
    float bd[16]; int bi[16];
#pragma unroll
    for (int m = 0; m < 16; ++m) { bd[m] = 1e30f; bi[m] = -1; }
    float wv = 1e30f; int wi = 0;

    const int ntile = (NPTS + 127) / 128;
    for (int tile = 0; tile < ntile; ++tile) {
        const int c0 = tile * 128;
        __syncthreads();   // prev selection done reading dT; cbuf free
#pragma unroll
        for (int i = 0; i < 4; ++i) {
            int ch = i*512 + t;
            int row = ch >> 4, off = ch & 15;
            uint4 v = make_uint4(0,0,0,0);
            if (c0 + row < NPTS) v = ((const uint4*)(x1 + (c0+row)*64))[off];
            *(uint4*)&cbuf[row*RP + off*8] = v;
        }
        if (t < 128) ssq[t] = (c0 + t < NPTS) ? sqv[c0 + t] : 1e30f;
        __syncthreads();

        f32x4 acc[4];
#pragma unroll
        for (int t4 = 0; t4 < 4; ++t4) acc[t4] = (f32x4){0.f,0.f,0.f,0.f};
#pragma unroll
        for (int t4 = 0; t4 < 4; ++t4) {
            const unsigned short* cr = &cbuf[(cs*64 + t4*16 + lane15)*RP + quad*8];
            bf16x8 Bh0 = *(const bf16x8*)(cr);
            bf16x8 Bh1 = *(const bf16x8*)(cr + 32);
            bf16x8 Bl0 = *(const bf16x8*)(cr + 64);
            bf16x8 Bl1 = *(const bf16x8*)(cr + 96);
            acc[t4] = __builtin_amdgcn_mfma_f32_16x16x32_bf16(Ah[0], Bh0, acc[t4], 0, 0, 0);
            acc[t4] = __builtin_amdgcn_mfma_f32_16x16x32_bf16(Al[0], Bh0, acc[t4], 0, 0, 0);
            acc[t4] = __builtin_amdgcn_mfma_f32_16x16x32_bf16(Ah[0], Bl0, acc[t4], 0, 0, 0);
            acc[t4] = __builtin_amdgcn_mfma_f32_16x16x32_bf16(Ah[1], Bh1, acc[t4], 0, 0, 0);
            acc[t4] = __builtin_amdgcn_mfma_f32_16x16x32_bf16(Al[1], Bh1, acc[t4], 0, 0, 0);
            acc[t4] = __builtin_amdgcn_mfma_f32_16x16x32_bf16(Ah[1], Bl1, acc[t4], 0, 0, 0);
        }
        __syncthreads();   // all cbuf reads done; dT may overwrite
#pragma unroll
        for (int t4 = 0; t4 < 4; ++t4) {
#pragma unroll
            for (int j = 0; j < 4; ++j)
                dT[(qs*16 + quad*4 + j)*DTP + cs*64 + t4*16 + lane15] = acc[t4][j];
        }
        __syncthreads();
        if (selact) {
#pragma unroll
            for (int ii = 0; ii < 8; ++ii) {
                int cc = sub*32 + ii*4;
                float4 dv = *(const float4*)&dT[selq*DTP + cc];
                float dd[4] = {dv.x, dv.y, dv.z, dv.w};
#pragma unroll
                for (int e = 0; e < 4; ++e) {
                    int cg = c0 + cc + e;
                    float d2 = ssq[cc+e] - 2.0f*dd[e];   // sqq dropped (per-query const)
                    if (d2 < wv && cg < NPTS) {
#pragma unroll
                        for (int m = 0; m < 16; ++m) if (m == wi) { bd[m] = d2; bi[m] = cg; }
                        wv = bd[0]; wi = 0;
#pragma unroll
                        for (int m = 1; m < 16; ++m) if (bd[m] > wv) { wv = bd[m]; wi = m; }
                    }
                }
            }
        }
    }
    __syncthreads();   // all staging regions dead; reuse as dump
    float* fd = (float*)qbuf;        // [64][65]
    int*   fi = (int*)cbuf_raw;      // [64][65]
    if (selact) {
#pragma unroll
        for (int m = 0; m < 16; ++m) {
            fd[selq*65 + sub*16 + m] = bd[m];
            fi[selq*65 + sub*16 + m] = bi[m];
        }
    }
    __syncthreads();
    if (t < 64 && n0 + t < NPTS) {
        const float* dls = fd + t*65;
        const int*   ils = fi + t*65;
        float lastd = -1e38f; int lasti = -1;
        for (int r = 0; r < 16; ++r) {
            float best = 1e30f; int bidx = 0;
            for (int m = 0; m < 64; ++m) {
                float dv2 = dls[m]; int iv = ils[m];
                bool gt = (dv2 > lastd) || (dv2 == lastd && iv > lasti);
                bool lt = (dv2 < best)  || (dv2 == best  && iv < bidx);
                if (gt && lt) { best = dv2; bidx = iv; }
            }
            int bc = bidx < 0 ? 0 : (bidx >= NPTS ? NPTS-1 : bidx);
            nbr[(n0 + t)*16 + r] = bc;
            lastd = best; lasti = bidx;
        }
    }
}

__device__ inline float bf2f(unsigned short u) {
    return __uint_as_float(((unsigned int)u) << 16);
}

// Fused stage-2 MLP (128->64->64, relu, max over 16 nbrs) + head. x1 rows are hi|lo bf16.
__global__ __launch_bounds__(64) void k_fuse(
    const float* __restrict__ x1, const int* __restrict__ nbr,
    const float* __restrict__ wb, float* __restrict__ out)
{
    __shared__ float sxr[64];
    __shared__ float svec[64];
    __shared__ float sx2[64];
    __shared__ int   snb[16];
    int n = blockIdx.x;
    int t = threadIdx.x;
    {
        const unsigned short* xr = (const unsigned short*)(x1 + n*64);
        sxr[t] = bf2f(xr[t]) + bf2f(xr[64+t]);
    }
    if (t < 16) snb[t] = nbr[n*16 + t];
    __syncthreads();
    const float* W2a = wb + WB_W2A;   // (128,64)
    const float* W2b = wb + WB_W2B;   // (64,64)
    float A = wb[WB_B2A + t];
    for (int i = 0; i < 64; ++i) A = fmaf(sxr[i], W2a[i*64 + t], A);
    float x2v = 0.0f;                 // z_k >= 0 (post-relu) -> 0-init == max
    for (int k = 0; k < 16; ++k) {
        int nb = snb[k];
        {
            const unsigned short* yr = (const unsigned short*)(x1 + nb*64);
            svec[t] = bf2f(yr[t]) + bf2f(yr[64+t]);
        }
        __syncthreads();
        float h = A;
        for (int i = 0; i < 64; ++i) h = fmaf(svec[i] - sxr[i], W2a[(64+i)*64 + t], h);
        h = fmaxf(h, 0.f);
        __syncthreads();
        svec[t] = h;
        __syncthreads();
        float z = wb[WB_B2B + t];
        for (int i = 0; i < 64; ++i) z = fmaf(svec[i], W2b[i*64 + t], z);
        x2v = fmaxf(x2v, fmaxf(z, 0.f));
        __syncthreads();
    }
    sx2[t] = x2v;
    __syncthreads();
    const float* We  = wb + WB_WE;
    const float* Wp  = wb + WB_WP;
    const float* Wr1 = wb + WB_WR1;
    const float* Wr2 = wb + WB_WR2;
    for (int r = 0; r < 4; ++r) {
        float xe = wb[WB_BE + r*64 + t];
        for (int i = 0; i < 64; ++i) xe = fmaf(sx2[i], We[i*256 + r*64 + t], xe);
        svec[t] = xe;
        __syncthreads();
        float ft = wb[WB_BP + t];
        for (int i = 0; i < 64; ++i) ft = fmaf(svec[i], Wp[i*64 + t], ft);
        __syncthreads();
        svec[t] = ft;
        __syncthreads();
        float hh = wb[WB_BR1 + t];
        for (int i = 0; i < 64; ++i) hh = fmaf(svec[i], Wr1[i*64 + t], hh);
        hh = fmaxf(hh, 0.f);
        __syncthreads();
        svec[t] = hh;
        __syncthreads();
        if (t < 3) {
            float o = wb[WB_BR2 + t];
            for (int i = 0; i < 64; ++i) o = fmaf(svec[i], Wr2[i*3 + t], o);
            int m = r * NPTS + n;
            out[m*3 + t] = o;
        }
        __syncthreads();
    }
}

extern "C" void kernel_launch(void* const* d_in, const int* in_sizes, int n_in,
                              void* d_out, int out_size, void* d_ws, size_t ws_size,
                              hipStream_t stream)
{
    const float* dep = (const float*)d_in[0];
    const float* W1a = (const float*)d_in[1];
    const float* b1a = (const float*)d_in[2];
    const float* W1b = (const float*)d_in[3];
    const float* b1b = (const float*)d_in[4];
    const float* W2a = (const float*)d_in[5];
    const float* b2a = (const float*)d_in[6];
    const float* W2b = (const float*)d_in[7];
    const float* b2b = (const float*)d_in[8];
    const float* We  = (const float*)d_in[9];
    const float* be  = (const float*)d_in[10];
    const float* Wp  = (const float*)d_in[11];
    const float* bp  = (const float*)d_in[12];
    const float* Wr1 = (const float*)d_in[13];
    const float* br1 = (const float*)d_in[14];
    const float* Wr2 = (const float*)d_in[15];
    const float* br2 = (const float*)d_in[16];
    const int* ei = (const int*)d_in[17];

    if (ws_size < WS_NEED_BYTES || d_ws == nullptr) {
        k_out_zero<<<(out_size + 255)/256, 256, 0, stream>>>((float*)d_out, out_size);
        return;
    }

    float* ws   = (float*)d_ws;
    float* x1   = ws + OFF_X1;
    float* sq   = ws + OFF_SQ;
    float* wbuf = ws + OFF_WB;
    int*   nbr  = (int*)(ws + OFF_NBR);

    k_zero<<<(NPTS*64/4 + 255)/256, 256, 0, stream>>>(x1, NPTS*64/4);
    k_prep<<<64, 256, 0, stream>>>(W1a,b1a,W1b,b1b,W2a,b2a,W2b,b2b,We,be,Wp,bp,Wr1,br1,Wr2,br2, wbuf);
    k_edge_mlp<<<NE/256, 256, 0, stream>>>(dep, ei, wbuf, (unsigned int*)x1);
    k_conv<<<(NPTS+255)/256, 256, 0, stream>>>(x1, sq);
    k_knn<<<(NPTS+63)/64, 512, 0, stream>>>(x1, sq, nbr);
    k_fuse<<<NPTS, 64, 0, stream>>>(x1, nbr, wbuf, (float*)d_out);
}

// Round 8
// 2406.837 us; speedup vs baseline: 1.7591x; 1.1383x over previous
//
#include <hip/hip_runtime.h>
#include <hip/hip_bf16.h>

#define NPTS 20000
#define NE   320000
#define KNNK 16

typedef __attribute__((ext_vector_type(8))) short bf16x8;
typedef __attribute__((ext_vector_type(4))) float f32x4;

// ---- ws layout (float offsets) ---- total 1,662,240 floats = 6,648,960 B
// x1 region: per-row 256B = [64 bf16 hi | 64 bf16 lo] after k_conv (fp32 before)
#define OFF_X1   0
#define OFF_SQ   (OFF_X1 + NPTS*64)          // 1,280,000
#define OFF_WB   (OFF_SQ + NPTS)             // 1,300,000
#define WB_W1A  0
#define WB_B1A  384
#define WB_W1BT 448
#define WB_B1B  4544
#define WB_W2A  4608      // (128,64)
#define WB_B2A  12800
#define WB_W2B  12864     // (64,64)
#define WB_B2B  16960
#define WB_WE   17024     // (64,256)
#define WB_BE   33408
#define WB_WP   33664
#define WB_BP   37760
#define WB_WR1  37824
#define WB_BR1  41920
#define WB_WR2  41984
#define WB_BR2  42176
#define WB_TOT  42240
#define OFF_NBR  (OFF_WB + WB_TOT)           // int32, 320,000
#define WS_TOT_FLOATS (OFF_NBR + NPTS*KNNK)
#define WS_NEED_BYTES ((size_t)WS_TOT_FLOATS * 4)

__global__ __launch_bounds__(256) void k_out_zero(float* out, int nelem) {
    int i = blockIdx.x * 256 + threadIdx.x;
    if (i < nelem) out[i] = 0.0f;
}

__global__ __launch_bounds__(256) void k_zero(float* p, int nfloat4) {
    int i = blockIdx.x * 256 + threadIdx.x;
    if (i < nfloat4) { float4 z = {0.f,0.f,0.f,0.f}; ((float4*)p)[i] = z; }
}

__global__ __launch_bounds__(256) void k_prep(
    const float* W1a, const float* b1a,
    const float* W1b, const float* b1b,
    const float* W2a, const float* b2a,
    const float* W2b, const float* b2b,
    const float* We,  const float* be,
    const float* Wp,  const float* bp,
    const float* Wr1, const float* br1,
    const float* Wr2, const float* br2,
    float* wb)
{
    int t = blockIdx.x * blockDim.x + threadIdx.x;
    int gs = gridDim.x * blockDim.x;
    for (int i = t; i < 384;  i += gs) wb[WB_W1A+i] = W1a[i];
    for (int i = t; i < 64;   i += gs) wb[WB_B1A+i] = b1a[i];
    for (int i = t; i < 4096; i += gs) { int j=i>>6, k=i&63; wb[WB_W1BT+i] = W1b[k*64+j]; }
    for (int i = t; i < 64;   i += gs) wb[WB_B1B+i] = b1b[i];
    for (int i = t; i < 8192; i += gs) wb[WB_W2A+i] = W2a[i];
    for (int i = t; i < 64;   i += gs) wb[WB_B2A+i] = b2a[i];
    for (int i = t; i < 4096; i += gs) wb[WB_W2B+i] = W2b[i];
    for (int i = t; i < 64;   i += gs) wb[WB_B2B+i] = b2b[i];
    for (int i = t; i < 16384;i += gs) wb[WB_WE+i]  = We[i];
    for (int i = t; i < 256;  i += gs) wb[WB_BE+i]  = be[i];
    for (int i = t; i < 4096; i += gs) wb[WB_WP+i]  = Wp[i];
    for (int i = t; i < 64;   i += gs) wb[WB_BP+i]  = bp[i];
    for (int i = t; i < 4096; i += gs) wb[WB_WR1+i] = Wr1[i];
    for (int i = t; i < 64;   i += gs) wb[WB_BR1+i] = br1[i];
    for (int i = t; i < 192;  i += gs) wb[WB_WR2+i] = Wr2[i];
    for (int i = t; i < 3;    i += gs) wb[WB_BR2+i] = br2[i];
}

// Stage 1: per-edge MLP (6->64->64, relu both) + atomic segment-max into x1 (fp32).
// Read-before-atomic: x1u is monotone non-decreasing, so a (possibly stale) read
// showing cur >= a is always safe to skip -> ~4x fewer global atomics.
__global__ __launch_bounds__(256) void k_edge_mlp(
    const float* __restrict__ dep, const int* __restrict__ ei,
    const float* __restrict__ wb, unsigned int* __restrict__ x1u)
{
    int e = blockIdx.x * 256 + threadIdx.x;
    if (e >= NE) return;
    int s = ei[e];
    int d = ei[NE + e];
    s = s < 0 ? 0 : (s >= NPTS ? NPTS-1 : s);
    d = d < 0 ? 0 : (d >= NPTS ? NPTS-1 : d);
    float xi0 = dep[d*3+0];
    float xi1 = dep[d*3+1];
    float xi2 = dep[d*3+2];
    float xj0 = dep[s*3+0];
    float xj1 = dep[s*3+1];
    float xj2 = dep[s*3+2];
    float in6[6] = { xi0, xi1, xi2, xj0-xi0, xj1-xi1, xj2-xi2 };
    const float* W1a  = wb + WB_W1A;
    const float* b1a  = wb + WB_B1A;
    const float* W1bT = wb + WB_W1BT;
    const float* b1b  = wb + WB_B1B;
    float h1[64];
#pragma unroll
    for (int j = 0; j < 64; ++j) {
        float a = b1a[j];
#pragma unroll
        for (int i = 0; i < 6; ++i) a = fmaf(in6[i], W1a[i*64+j], a);
        h1[j] = fmaxf(a, 0.0f);
    }
    unsigned int* dst = x1u + d*64;
    int woff = (((blockIdx.x << 2) + (threadIdx.x >> 6)) & 3) << 4;  // wave-uniform
    for (int j = 0; j < 64; ++j) {
        int jj = (j + woff) & 63;
        float a = b1b[jj];
        const float* wr = W1bT + jj*64;
#pragma unroll
        for (int i = 0; i < 64; ++i) a = fmaf(h1[i], wr[i], a);
        a = fmaxf(a, 0.0f);
        unsigned int au = __float_as_uint(a);
        if (au > dst[jj]) atomicMax(dst + jj, au);
    }
}

// Convert x1 rows fp32 -> [hi bf16 x64 | lo bf16 x64] IN PLACE, and write sq (from fp32).
__global__ __launch_bounds__(256) void k_conv(float* __restrict__ x1, float* __restrict__ sq) {
    int n = blockIdx.x * 256 + threadIdx.x;
    if (n >= NPTS) return;
    float* base = x1 + n*64;
    float4 r[16];
#pragma unroll
    for (int i = 0; i < 16; ++i) r[i] = ((const float4*)base)[i];
    float s = 0.f;
#pragma unroll
    for (int i = 0; i < 16; ++i) s += r[i].x*r[i].x + r[i].y*r[i].y + r[i].z*r[i].z + r[i].w*r[i].w;
    sq[n] = s;
    unsigned int* hi = (unsigned int*)base;          // bytes [0,128)
    unsigned int* lo = (unsigned int*)(base + 32);   // bytes [128,256)
#pragma unroll
    for (int j = 0; j < 8; ++j) {
        float v[8] = { r[2*j].x, r[2*j].y, r[2*j].z, r[2*j].w,
                       r[2*j+1].x, r[2*j+1].y, r[2*j+1].z, r[2*j+1].w };
        unsigned int hb[8], lb[8];
#pragma unroll
        for (int e = 0; e < 8; ++e) {
            unsigned int u = __float_as_uint(v[e]);
            hb[e] = (u + 0x7fffu + ((u >> 16) & 1u)) >> 16;           // RNE bf16
            float hf = __uint_as_float(hb[e] << 16);
            float lf = v[e] - hf;
            unsigned int ul = __float_as_uint(lf);
            lb[e] = (ul + 0x7fffu + ((ul >> 16) & 1u)) >> 16;
        }
        uint4 hp, lp;
        hp.x = hb[0] | (hb[1] << 16); hp.y = hb[2] | (hb[3] << 16);
        hp.z = hb[4] | (hb[5] << 16); hp.w = hb[6] | (hb[7] << 16);
        lp.x = lb[0] | (lb[1] << 16); lp.y = lb[2] | (lb[3] << 16);
        lp.z = lb[4] | (lb[5] << 16); lp.w = lb[6] | (lb[7] << 16);
        ((uint4*)hi)[j] = hp;
        ((uint4*)lo)[j] = lp;
    }
}

// KNN v4 (MFMA split-bf16): 512 threads, 64q x 128c tiles, 3 blocks/CU (51.5 KB LDS).
// dT TRANSPOSED [c][q] pitch 68: MFMA C-regs (4 consecutive rows/lane) store b128;
// selection reads stride-68 b32 (2-way, free). Tile-skip selection: scan 16-cand
// chunks into regs (fma+min only), run update pass only if chunk-min < wv.
#define RP  136   // staging row pitch in shorts (272 B): balanced banks
#define DTQ 68    // dT pitch in words ([c][q])
__global__ __launch_bounds__(512, 6) void k_knn(
    const float* __restrict__ x1, const float* __restrict__ sqv,
    int* __restrict__ nbr)
{
    __shared__ __align__(16) unsigned short qbuf[64*RP];        // 17408 B
    __shared__ __align__(16) unsigned char  cbuf_raw[128*RP*2]; // 34816 B (c-tiles, dT alias)
    __shared__ float ssq[128];
    unsigned short* cbuf = (unsigned short*)cbuf_raw;           // [128][RP]
    float* dT = (float*)cbuf_raw;                               // [128 c][DTQ q]
    const int t  = threadIdx.x;
    const int n0 = blockIdx.x * 64;

    // stage q tile: 64 rows x 256 B (hi|lo) -> qbuf rows
#pragma unroll
    for (int i = 0; i < 2; ++i) {
        int ch = i*512 + t;
        int row = ch >> 4, off = ch & 15;
        uint4 v = make_uint4(0,0,0,0);
        if (n0 + row < NPTS) v = ((const uint4*)(x1 + (n0+row)*64))[off];
        *(uint4*)&qbuf[row*RP + off*8] = v;
    }
    __syncthreads();

    const int lane15 = t & 15;
    const int quad   = (t >> 4) & 3;
    const int w  = t >> 6;
    const int qs = w >> 1, cs = w & 1;
    bf16x8 Ah[2], Al[2];
    {
        const unsigned short* qr = &qbuf[(qs*16 + lane15)*RP + quad*8];
        Ah[0] = *(const bf16x8*)(qr);
        Ah[1] = *(const bf16x8*)(qr + 32);
        Al[0] = *(const bf16x8*)(qr + 64);
        Al[1] = *(const bf16x8*)(qr + 96);
    }
    const int selq = t & 63, sub = (t >> 6) & 3;
    const bool selact = (t < 256);
    float bd[16]; int bi[16];
#pragma unroll
    for (int m = 0; m < 16; ++m) { bd[m] = 1e30f; bi[m] = -1; }
    float wv = 1e30f; int wi = 0;

    const int ntile = (NPTS + 127) / 128;
    for (int tile = 0; tile < ntile; ++tile) {
        const int c0 = tile * 128;
        __syncthreads();   // prev selection done reading dT; cbuf free
#pragma unroll
        for (int i = 0; i < 4; ++i) {
            int ch = i*512 + t;
            int row = ch >> 4, off = ch & 15;
            uint4 v = make_uint4(0,0,0,0);
            if (c0 + row < NPTS) v = ((const uint4*)(x1 + (c0+row)*64))[off];
            *(uint4*)&cbuf[row*RP + off*8] = v;
        }
        if (t < 128) ssq[t] = (c0 + t < NPTS) ? sqv[c0 + t] : 1e30f;
        __syncthreads();

        f32x4 acc[4];
#pragma unroll
        for (int t4 = 0; t4 < 4; ++t4) acc[t4] = (f32x4){0.f,0.f,0.f,0.f};
#pragma unroll
        for (int t4 = 0; t4 < 4; ++t4) {
            const unsigned short* cr = &cbuf[(cs*64 + t4*16 + lane15)*RP + quad*8];
            bf16x8 Bh0 = *(const bf16x8*)(cr);
            bf16x8 Bh1 = *(const bf16x8*)(cr + 32);
            bf16x8 Bl0 = *(const bf16x8*)(cr + 64);
            bf16x8 Bl1 = *(const bf16x8*)(cr + 96);
            acc[t4] = __builtin_amdgcn_mfma_f32_16x16x32_bf16(Ah[0], Bh0, acc[t4], 0, 0, 0);
            acc[t4] = __builtin_amdgcn_mfma_f32_16x16x32_bf16(Al[0], Bh0, acc[t4], 0, 0, 0);
            acc[t4] = __builtin_amdgcn_mfma_f32_16x16x32_bf16(Ah[0], Bl0, acc[t4], 0, 0, 0);
            acc[t4] = __builtin_amdgcn_mfma_f32_16x16x32_bf16(Ah[1], Bh1, acc[t4], 0, 0, 0);
            acc[t4] = __builtin_amdgcn_mfma_f32_16x16x32_bf16(Al[1], Bh1, acc[t4], 0, 0, 0);
            acc[t4] = __builtin_amdgcn_mfma_f32_16x16x32_bf16(Ah[1], Bl1, acc[t4], 0, 0, 0);
        }
        __syncthreads();   // all cbuf reads done; dT may overwrite
        // dT[c][q]: lane's 4 acc entries are 4 consecutive q rows -> one b128 per t4
#pragma unroll
        for (int t4 = 0; t4 < 4; ++t4) {
            int c = cs*64 + t4*16 + lane15;
            float4 o; o.x = acc[t4][0]; o.y = acc[t4][1]; o.z = acc[t4][2]; o.w = acc[t4][3];
            *(float4*)&dT[c*DTQ + qs*16 + quad*4] = o;
        }
        __syncthreads();
        if (selact) {
#pragma unroll
            for (int half = 0; half < 2; ++half) {
                int cbase = sub*32 + half*16;
                float d2r[16];
                float minv = 1e30f;
#pragma unroll
                for (int ii = 0; ii < 16; ++ii) {
                    float dot = dT[(cbase + ii)*DTQ + selq];
                    float d2 = fmaf(-2.0f, dot, ssq[cbase + ii]);
                    d2r[ii] = d2;
                    minv = fminf(minv, d2);
                }
                if (minv < wv) {
#pragma unroll
                    for (int ii = 0; ii < 16; ++ii) {
                        float d2 = d2r[ii];
                        if (d2 < wv) {
                            int cg = c0 + cbase + ii;
#pragma unroll
                            for (int m = 0; m < 16; ++m) if (m == wi) { bd[m] = d2; bi[m] = cg; }
                            wv = bd[0]; wi = 0;
#pragma unroll
                            for (int m = 1; m < 16; ++m) if (bd[m] > wv) { wv = bd[m]; wi = m; }
                        }
                    }
                }
            }
        }
    }
    __syncthreads();   // all staging regions dead; reuse as dump
    float* fd = (float*)qbuf;        // [64][65]
    int*   fi = (int*)cbuf_raw;      // [64][65]
    if (selact) {
#pragma unroll
        for (int m = 0; m < 16; ++m) {
            fd[selq*65 + sub*16 + m] = bd[m];
            fi[selq*65 + sub*16 + m] = bi[m];
        }
    }
    __syncthreads();
    if (t < 64 && n0 + t < NPTS) {
        const float* dls = fd + t*65;
        const int*   ils = fi + t*65;
        float lastd = -1e38f; int lasti = -1;
        for (int r = 0; r < 16; ++r) {
            float best = 1e30f; int bidx = 0;
            for (int m = 0; m < 64; ++m) {
                float dv2 = dls[m]; int iv = ils[m];
                bool gt = (dv2 > lastd) || (dv2 == lastd && iv > lasti);
                bool lt = (dv2 < best)  || (dv2 == best  && iv < bidx);
                if (gt && lt) { best = dv2; bidx = iv; }
            }
            int bc = bidx < 0 ? 0 : (bidx >= NPTS ? NPTS-1 : bidx);
            nbr[(n0 + t)*16 + r] = bc;
            lastd = best; lasti = bidx;
        }
    }
}

__device__ inline float bf2f(unsigned short u) {
    return __uint_as_float(((unsigned int)u) << 16);
}

// Fused stage-2 MLP (128->64->64, relu, max over 16 nbrs) + head. x1 rows are hi|lo bf16.
// float4 LDS reads in all dot loops.
__global__ __launch_bounds__(64) void k_fuse(
    const float* __restrict__ x1, const int* __restrict__ nbr,
    const float* __restrict__ wb, float* __restrict__ out)
{
    __shared__ __align__(16) float sxr[64];
    __shared__ __align__(16) float svec[64];
    __shared__ __align__(16) float sx2[64];
    __shared__ int snb[16];
    int n = blockIdx.x;
    int t = threadIdx.x;
    {
        const unsigned short* xr = (const unsigned short*)(x1 + n*64);
        sxr[t] = bf2f(xr[t]) + bf2f(xr[64+t]);
    }
    if (t < 16) snb[t] = nbr[n*16 + t];
    __syncthreads();
    const float* W2a = wb + WB_W2A;   // (128,64)
    const float* W2b = wb + WB_W2B;   // (64,64)
    const float4* sx4 = (const float4*)sxr;
    const float4* sv4 = (const float4*)svec;
    float A = wb[WB_B2A + t];
#pragma unroll
    for (int i4 = 0; i4 < 16; ++i4) {
        float4 v = sx4[i4];
        const float* wr = W2a + i4*256 + t;
        A = fmaf(v.x, wr[0], A); A = fmaf(v.y, wr[64], A);
        A = fmaf(v.z, wr[128], A); A = fmaf(v.w, wr[192], A);
    }
    float x2v = 0.0f;                 // z_k >= 0 (post-relu) -> 0-init == max
    for (int k = 0; k < 16; ++k) {
        int nb = snb[k];
        {
            const unsigned short* yr = (const unsigned short*)(x1 + nb*64);
            svec[t] = bf2f(yr[t]) + bf2f(yr[64+t]);
        }
        __syncthreads();
        float h = A;
#pragma unroll
        for (int i4 = 0; i4 < 16; ++i4) {
            float4 v = sv4[i4];
            float4 u = sx4[i4];
            const float* wr = W2a + (64 + i4*4)*64 + t;
            h = fmaf(v.x-u.x, wr[0], h); h = fmaf(v.y-u.y, wr[64], h);
            h = fmaf(v.z-u.z, wr[128], h); h = fmaf(v.w-u.w, wr[192], h);
        }
        h = fmaxf(h, 0.f);
        __syncthreads();
        svec[t] = h;
        __syncthreads();
        float z = wb[WB_B2B + t];
#pragma unroll
        for (int i4 = 0; i4 < 16; ++i4) {
            float4 v = sv4[i4];
            const float* wr = W2b + i4*256 + t;
            z = fmaf(v.x, wr[0], z); z = fmaf(v.y, wr[64], z);
            z = fmaf(v.z, wr[128], z); z = fmaf(v.w, wr[192], z);
        }
        x2v = fmaxf(x2v, fmaxf(z, 0.f));
        __syncthreads();
    }
    sx2[t] = x2v;
    __syncthreads();
    const float4* sx24 = (const float4*)sx2;
    const float* We  = wb + WB_WE;
    const float* Wp  = wb + WB_WP;
    const float* Wr1 = wb + WB_WR1;
    const float* Wr2 = wb + WB_WR2;
    for (int r = 0; r < 4; ++r) {
        float xe = wb[WB_BE + r*64 + t];
#pragma unroll
        for (int i4 = 0; i4 < 16; ++i4) {
            float4 v = sx24[i4];
            const float* wr = We + i4*1024 + r*64 + t;
            xe = fmaf(v.x, wr[0], xe); xe = fmaf(v.y, wr[256], xe);
            xe = fmaf(v.z, wr[512], xe); xe = fmaf(v.w, wr[768], xe);
        }
        svec[t] = xe;
        __syncthreads();
        float ft = wb[WB_BP + t];
#pragma unroll
        for (int i4 = 0; i4 < 16; ++i4) {
            float4 v = sv4[i4];
            const float* wr = Wp + i4*256 + t;
            ft = fmaf(v.x, wr[0], ft); ft = fmaf(v.y, wr[64], ft);
            ft = fmaf(v.z, wr[128], ft); ft = fmaf(v.w, wr[192], ft);
        }
        __syncthreads();
        svec[t] = ft;
        __syncthreads();
        float hh = wb[WB_BR1 + t];
#pragma unroll
        for (int i4 = 0; i4 < 16; ++i4) {
            float4 v = sv4[i4];
            const float* wr = Wr1 + i4*256 + t;
            hh = fmaf(v.x, wr[0], hh); hh = fmaf(v.y, wr[64], hh);
            hh = fmaf(v.z, wr[128], hh); hh = fmaf(v.w, wr[192], hh);
        }
        hh = fmaxf(hh, 0.f);
        __syncthreads();
        svec[t] = hh;
        __syncthreads();
        if (t < 3) {
            float o = wb[WB_BR2 + t];
            for (int i = 0; i < 64; ++i) o = fmaf(svec[i], Wr2[i*3 + t], o);
            int m = r * NPTS + n;
            out[m*3 + t] = o;
        }
        __syncthreads();
    }
}

extern "C" void kernel_launch(void* const* d_in, const int* in_sizes, int n_in,
                              void* d_out, int out_size, void* d_ws, size_t ws_size,
                              hipStream_t stream)
{
    const float* dep = (const float*)d_in[0];
    const float* W1a = (const float*)d_in[1];
    const float* b1a = (const float*)d_in[2];
    const float* W1b = (const float*)d_in[3];
    const float* b1b = (const float*)d_in[4];
    const float* W2a = (const float*)d_in[5];
    const float* b2a = (const float*)d_in[6];
    const float* W2b = (const float*)d_in[7];
    const float* b2b = (const float*)d_in[8];
    const float* We  = (const float*)d_in[9];
    const float* be  = (const float*)d_in[10];
    const float* Wp  = (const float*)d_in[11];
    const float* bp  = (const float*)d_in[12];
    const float* Wr1 = (const float*)d_in[13];
    const float* br1 = (const float*)d_in[14];
    const float* Wr2 = (const float*)d_in[15];
    const float* br2 = (const float*)d_in[16];
    const int* ei = (const int*)d_in[17];

    if (ws_size < WS_NEED_BYTES || d_ws == nullptr) {
        k_out_zero<<<(out_size + 255)/256, 256, 0, stream>>>((float*)d_out, out_size);
        return;
    }

    float* ws   = (float*)d_ws;
    float* x1   = ws + OFF_X1;
    float* sq   = ws + OFF_SQ;
    float* wbuf = ws + OFF_WB;
    int*   nbr  = (int*)(ws + OFF_NBR);

    k_zero<<<(NPTS*64/4 + 255)/256, 256, 0, stream>>>(x1, NPTS*64/4);
    k_prep<<<64, 256, 0, stream>>>(W1a,b1a,W1b,b1b,W2a,b2a,W2b,b2b,We,be,Wp,bp,Wr1,br1,Wr2,br2, wbuf);
    k_edge_mlp<<<NE/256, 256, 0, stream>>>(dep, ei, wbuf, (unsigned int*)x1);
    k_conv<<<(NPTS+255)/256, 256, 0, stream>>>(x1, sq);
    k_knn<<<(NPTS+63)/64, 512, 0, stream>>>(x1, sq, nbr);
    k_fuse<<<NPTS, 64, 0, stream>>>(x1, nbr, wbuf, (float*)d_out);
}